// Round 3
// baseline (109.028 us; speedup 1.0000x reference)
//
#include <hip/hip_runtime.h>

#define EPSF 1e-6f
#define POISON 0xAAAAAAAAu
// DPP ctrl codes: XOR-lane shuffles (symmetric -> no direction ambiguity)
#define X1  0xB1    // quad_perm [1,0,3,2]  : lane ^= 1
#define X3  0x1B    // quad_perm [3,2,1,0]  : lane ^= 3
#define X7  0x141   // row_half_mirror      : lane ^= 7
#define X15 0x140   // row_mirror           : lane ^= 15

template<int C>
__device__ __forceinline__ float dppf(float x) {
    return __int_as_float(__builtin_amdgcn_update_dpp(0, __float_as_int(x), C, 0xF, 0xF, true));
}

__device__ __forceinline__ float wave_sum(float v) {
#pragma unroll
    for (int off = 32; off; off >>= 1) v += __shfl_down(v, off, 64);
    return v;
}

// 512 blocks (one per image row) x 512 threads (one pixel each).
// Column-min rotation network: per 16-column chunk, each 16-lane row loads one
// {dy^2, gx} per lane (1 ds_read_b64/chunk) and rotates column data + column
// accumulator through the 16 lanes via XOR-DPP (masks m_i = i^(i+1), all in
// {1,3,7,15}). Cumulative mask after i steps = i, so lane s holds column s^i;
// after 16 steps everything is home. Zero DS ops in the steady-state iter.
__launch_bounds__(512, 4)
__global__ void chamfer_fused(const float* __restrict__ prob,
                              const float* __restrict__ gt,
                              float* __restrict__ out,
                              float* __restrict__ sums,        // [0]=sum p, [1]=sum p*d
                              unsigned int* __restrict__ cnt,
                              unsigned int* __restrict__ g_cm) // [32 slots][512]
{
    __shared__ float2 dg_s[512];          // {dy^2, gx} per GT point
    __shared__ unsigned int cm_s[512];    // block column mins (float bits)
    __shared__ float red[16];
    __shared__ int last_s;

    const int t = threadIdx.x;
    const int row = blockIdx.x;
    const float maxd = __builtin_sqrtf(524288.0f);   // sqrt(512^2+512^2), folded

    // stage GT: thread t handles point t
    float2 gv = ((const float2*)gt)[t];              // (gy, gx)
    float dyr = (float)row - gv.x;
    dg_s[t] = make_float2(dyr * dyr, gv.y);
    cm_s[t] = 0x7F800000u;                           // +inf bits

    const float p   = prob[(row << 9) + t];
    const float p2  = p * p;
    const float inv = 1.0f / (p2 * p2 + EPSF / maxd);
    const float isq = inv * inv;                     // s = sqrt(d2*inv^2) + eps*inv
    const float ei  = EPSF * inv;
    const float tf  = (float)t;
    float rm = 3.0e38f;                              // row min of d^2 (sqrt deferred)

    __syncthreads();

    const int s16 = t & 15;
    float2 g = dg_s[s16];                            // chunk 0 prefetch

#define BODY(MACC, MG) { \
        float dx = tf - gx; \
        float d2 = fmaf(dx, dx, dy2); \
        rm = fminf(rm, d2); \
        float sv = __builtin_amdgcn_sqrtf(d2 * isq) + ei; \
        acc = fminf(dppf<MACC>(acc), sv); \
        gx = dppf<MG>(gx); dy2 = dppf<MG>(dy2); }

    for (int k = 0; k < 32; ++k) {
        float gx = g.y, dy2 = g.x;
        float2 gn = dg_s[(((k + 1) & 31) << 4) + s16];  // prefetch next chunk
        float acc;
        {   // step 0: acc = first value (no min needed)
            float dx = tf - gx;
            float d2 = fmaf(dx, dx, dy2);
            rm = fminf(rm, d2);
            acc = __builtin_amdgcn_sqrtf(d2 * isq) + ei;
            gx = dppf<X1>(gx); dy2 = dppf<X1>(dy2);
        }
        BODY(X1,  X3)   // i=1
        BODY(X3,  X1)   // 2
        BODY(X1,  X7)   // 3
        BODY(X7,  X1)   // 4
        BODY(X1,  X3)   // 5
        BODY(X3,  X1)   // 6
        BODY(X1,  X15)  // 7
        BODY(X15, X1)   // 8
        BODY(X1,  X3)   // 9
        BODY(X3,  X1)   // 10
        BODY(X1,  X7)   // 11
        BODY(X7,  X1)   // 12
        BODY(X1,  X3)   // 13
        BODY(X3,  X1)   // 14
        {   // step 15: column data rotation is dead, skip it
            float dx = tf - gx;
            float d2 = fmaf(dx, dx, dy2);
            rm = fminf(rm, d2);
            float sv = __builtin_amdgcn_sqrtf(d2 * isq) + ei;
            acc = fminf(dppf<X1>(acc), sv);
        }
        acc = dppf<X15>(acc);                        // m_15: rotate acc home
        atomicMin(&cm_s[(k << 4) + s16], __float_as_uint(acc)); // 4-way/addr
        g = gn;
    }
#undef BODY

    __syncthreads();

    // merge block colmins into 32-slot global array (poison 0xAAAAAAAA is a
    // valid uint-min identity: > any positive-float bit pattern)
    atomicMin(&g_cm[((row & 31) << 9) + t], cm_s[t]);

    // term1 partials: d = sqrt(min d^2)
    float dmin = __builtin_amdgcn_sqrtf(rm);
    float pv = wave_sum(p * dmin);
    float sp = wave_sum(p);
    if ((t & 63) == 0) { red[t >> 6] = pv; red[8 + (t >> 6)] = sp; }
    __syncthreads();
    if (t == 0) {
        float a = 0.f, b = 0.f;
#pragma unroll
        for (int i = 0; i < 8; ++i) { a += red[i]; b += red[8 + i]; }
        atomicAdd(&sums[1], a);     // poison -3e-13f absorbed by fp32 add
        atomicAdd(&sums[0], b);
        __threadfence();
        unsigned int old = atomicAdd(cnt, 1u);
        last_s = (old == POISON + 511u) || (old == 511u);
    }
    __syncthreads();
    if (!last_s) return;

    // ---- last block: finalize ----
    __threadfence();
    unsigned int mv = __hip_atomic_load(&g_cm[t], __ATOMIC_RELAXED, __HIP_MEMORY_SCOPE_AGENT);
#pragma unroll
    for (int sl = 1; sl < 32; ++sl) {
        unsigned int u = __hip_atomic_load(&g_cm[(sl << 9) + t], __ATOMIC_RELAXED, __HIP_MEMORY_SCOPE_AGENT);
        mv = (u < mv) ? u : mv;
    }
    float v = fminf(fmaxf(__uint_as_float(mv), 0.0f), maxd);
    float s2 = wave_sum(v);
    if ((t & 63) == 0) red[t >> 6] = s2;
    __syncthreads();
    if (t == 0) {
        float tsum = 0.f;
#pragma unroll
        for (int i = 0; i < 8; ++i) tsum += red[i];
        float term2 = tsum * (1.0f / 512.0f);
        float sA = __hip_atomic_load(&sums[0], __ATOMIC_RELAXED, __HIP_MEMORY_SCOPE_AGENT);
        float sB = __hip_atomic_load(&sums[1], __ATOMIC_RELAXED, __HIP_MEMORY_SCOPE_AGENT);
        out[0] = sB / (sA + EPSF) + term2;
    }
}

extern "C" void kernel_launch(void* const* d_in, const int* in_sizes, int n_in,
                              void* d_out, int out_size, void* d_ws, size_t ws_size,
                              hipStream_t stream) {
    const float* prob = (const float*)d_in[0];   // [512*512]
    const float* gt   = (const float*)d_in[1];   // [512,2]
    // d_in[2] (all_img_locations) implicit from pixel index; unused.
    float* out = (float*)d_out;

    float* sums        = (float*)d_ws;                            // 8 B
    unsigned int* cnt  = (unsigned int*)((char*)d_ws + 8);        // 4 B
    unsigned int* g_cm = (unsigned int*)((char*)d_ws + 128);      // 64 KB

    chamfer_fused<<<512, 512, 0, stream>>>(prob, gt, out, sums, cnt, g_cm);
}

// Round 4
// 93.463 us; speedup vs baseline: 1.1665x; 1.1665x over previous
//
#include <hip/hip_runtime.h>

#define EPSF 1e-6f
#define POISON 0xAAAAAAAAu
#define INFB 0x7F800000u

__device__ __forceinline__ float wave_sum(float v) {
#pragma unroll
    for (int off = 32; off; off >>= 1) v += __shfl_down(v, off, 64);
    return v;
}

// 512 blocks (one per image row) x 512 threads.
// Thread (g = t>>7, s = t&127): owns pixels x = s+{0,128,256,384} of this row
// and GT chunk g (128 points). Per iter: 1 ds_read_b64 + 1 ds_min amortized
// over 4 pixel-pairs; row-min kept in registers on d^2 (sqrt deferred).
// Chunk-mirrored LDS arrays (two copies per 128-entry chunk) make the GT
// index linear (no wrap) and keep a wave's ds_min addresses at 64 consecutive
// dwords (2-way bank alias = free).
// Workspace poison contract (0xAA): g_cm uint-min identity (0xAAAAAAAA > any
// positive-float bits); sums poison -3.03e-13f absorbed by fp32 +=; cnt
// last-block check accepts POISON+511 (and 511 fallback).
__launch_bounds__(512, 4)
__global__ void chamfer_fused(const float* __restrict__ prob,
                              const float* __restrict__ gt,
                              float* __restrict__ out,
                              float* __restrict__ sums,        // [0]=sum p, [1]=sum p*d
                              unsigned int* __restrict__ cnt,
                              unsigned int* __restrict__ g_cm) // [16 slots][512]
{
    __shared__ float2 dg_s[1024];        // chunk-mirrored {dy^2, gx}
    __shared__ unsigned int cm_s[1024];  // chunk-mirrored column-min bits
    __shared__ unsigned int rm_s[512];   // per-pixel row-min d^2 bits
    __shared__ float p_s[512];
    __shared__ float red[16];
    __shared__ int last_s;

    const int t = threadIdx.x;
    const int row = blockIdx.x;
    const int g = t >> 7;
    const int s = t & 127;
    const float maxd = __builtin_sqrtf(524288.0f);   // sqrt(512^2+512^2)

    // ---- stage GT (chunk-mirrored), prob row, init mins
    {
        float2 gv = ((const float2*)gt)[t];          // (gy, gx)
        float dy = (float)row - gv.x;
        float2 v = make_float2(dy * dy, gv.y);
        dg_s[(g << 8) + s]       = v;
        dg_s[(g << 8) + 128 + s] = v;
    }
    cm_s[t]       = INFB;
    cm_s[t + 512] = INFB;
    rm_s[t]       = INFB;
    p_s[t] = prob[(row << 9) + t];
    __syncthreads();

    // ---- per-pixel constants (4 px: s + 128k)
    float isq0, isq1, isq2, isq3, ei0, ei1, ei2, ei3;
    {
        float p0 = p_s[s], p1 = p_s[s + 128], p2 = p_s[s + 256], p3 = p_s[s + 384];
        float q0 = p0 * p0, q1 = p1 * p1, q2 = p2 * p2, q3 = p3 * p3;
        float i0 = 1.0f / (q0 * q0 + EPSF / maxd);
        float i1 = 1.0f / (q1 * q1 + EPSF / maxd);
        float i2 = 1.0f / (q2 * q2 + EPSF / maxd);
        float i3 = 1.0f / (q3 * q3 + EPSF / maxd);
        isq0 = i0 * i0; isq1 = i1 * i1; isq2 = i2 * i2; isq3 = i3 * i3;
        ei0 = EPSF * i0; ei1 = EPSF * i1; ei2 = EPSF * i2; ei3 = EPSF * i3;
    }
    const float sf = (float)s;
    float rm0 = 3e38f, rm1 = 3e38f, rm2 = 3e38f, rm3 = 3e38f;

    // ---- main loop: 128 GT points, 4 pixels each, prefetched
    int j = (g << 8) + s;
    float2 gc = dg_s[j];
#pragma unroll 8
    for (int i = 0; i < 128; ++i) {
        float2 gn = dg_s[j + 1];                 // prefetch next (mirror: in-range)
        float dx0 = sf - gc.y;
        float dx1 = dx0 + 128.0f;
        float dx2 = dx0 + 256.0f;
        float dx3 = dx0 + 384.0f;
        float d20 = fmaf(dx0, dx0, gc.x);
        float d21 = fmaf(dx1, dx1, gc.x);
        float d22 = fmaf(dx2, dx2, gc.x);
        float d23 = fmaf(dx3, dx3, gc.x);
        rm0 = fminf(rm0, d20); rm1 = fminf(rm1, d21);
        rm2 = fminf(rm2, d22); rm3 = fminf(rm3, d23);
        float v0 = __builtin_amdgcn_sqrtf(d20 * isq0) + ei0;   // d*inv + eps*inv
        float v1 = __builtin_amdgcn_sqrtf(d21 * isq1) + ei1;
        float v2 = __builtin_amdgcn_sqrtf(d22 * isq2) + ei2;
        float v3 = __builtin_amdgcn_sqrtf(d23 * isq3) + ei3;
        float vm = fminf(fminf(v0, v1), fminf(v2, v3));
        atomicMin(&cm_s[j], __float_as_uint(vm));    // 64 consecutive dwords/wave
        gc = gn; ++j;
    }

    // ---- row-min merge across the 4 GT groups (positive floats: bit-ordered)
    atomicMin(&rm_s[s],       __float_as_uint(rm0));
    atomicMin(&rm_s[s + 128], __float_as_uint(rm1));
    atomicMin(&rm_s[s + 256], __float_as_uint(rm2));
    atomicMin(&rm_s[s + 384], __float_as_uint(rm3));
    __syncthreads();

    // ---- column merge (fold mirror halves), scatter into 16 global slots
    {
        unsigned int a = min(cm_s[(g << 8) + s], cm_s[(g << 8) + 128 + s]);
        atomicMin(&g_cm[((row & 15) << 9) + t], a);
    }

    // ---- term1 partials
    float dmin = __builtin_amdgcn_sqrtf(__uint_as_float(rm_s[t]));
    float pv = wave_sum(p_s[t] * dmin);
    float sp = wave_sum(p_s[t]);
    if ((t & 63) == 0) { red[t >> 6] = pv; red[8 + (t >> 6)] = sp; }
    __syncthreads();
    if (t == 0) {
        float a = 0.f, b = 0.f;
#pragma unroll
        for (int i = 0; i < 8; ++i) { a += red[i]; b += red[8 + i]; }
        atomicAdd(&sums[1], a);
        atomicAdd(&sums[0], b);
        __threadfence();
        unsigned int old = atomicAdd(cnt, 1u);
        last_s = (old == POISON + 511u) || (old == 511u);
    }
    __syncthreads();
    if (!last_s) return;

    // ---- last block finalizes
    __threadfence();
    unsigned int mv = __hip_atomic_load(&g_cm[t], __ATOMIC_RELAXED, __HIP_MEMORY_SCOPE_AGENT);
#pragma unroll
    for (int sl = 1; sl < 16; ++sl) {
        unsigned int u = __hip_atomic_load(&g_cm[(sl << 9) + t], __ATOMIC_RELAXED, __HIP_MEMORY_SCOPE_AGENT);
        mv = (u < mv) ? u : mv;
    }
    float v = fminf(fmaxf(__uint_as_float(mv), 0.0f), maxd);
    float s2 = wave_sum(v);
    if ((t & 63) == 0) red[t >> 6] = s2;
    __syncthreads();
    if (t == 0) {
        float tsum = 0.f;
#pragma unroll
        for (int i = 0; i < 8; ++i) tsum += red[i];
        float term2 = tsum * (1.0f / 512.0f);
        float sA = __hip_atomic_load(&sums[0], __ATOMIC_RELAXED, __HIP_MEMORY_SCOPE_AGENT);
        float sB = __hip_atomic_load(&sums[1], __ATOMIC_RELAXED, __HIP_MEMORY_SCOPE_AGENT);
        out[0] = sB / (sA + EPSF) + term2;
    }
}

extern "C" void kernel_launch(void* const* d_in, const int* in_sizes, int n_in,
                              void* d_out, int out_size, void* d_ws, size_t ws_size,
                              hipStream_t stream) {
    const float* prob = (const float*)d_in[0];   // [512*512]
    const float* gt   = (const float*)d_in[1];   // [512,2]
    // d_in[2] (all_img_locations) implicit from pixel index; unused.
    float* out = (float*)d_out;

    float* sums        = (float*)d_ws;                        // 8 B
    unsigned int* cnt  = (unsigned int*)((char*)d_ws + 8);    // 4 B
    unsigned int* g_cm = (unsigned int*)((char*)d_ws + 128);  // 16*512*4 = 32 KB

    chamfer_fused<<<512, 512, 0, stream>>>(prob, gt, out, sums, cnt, g_cm);
}

// Round 5
// 90.633 us; speedup vs baseline: 1.2030x; 1.0312x over previous
//
#include <hip/hip_runtime.h>

#define EPSF 1e-6f
#define POISON 0xAAAAAAAAu
#define INFB 0x7F800000u

__device__ __forceinline__ float wave_sum(float v) {
#pragma unroll
    for (int off = 32; off; off >>= 1) v += __shfl_down(v, off, 64);
    return v;
}

// 512 blocks (one per image row) x 512 threads.
// Thread (g = t>>6, s = t&63): owns pixels x = s+{0,64,...,448} (8 px) and GT
// chunk g (64 points). A wave == one GT group -> wave-uniform chunk base; the
// per-iter ds_min hits 64 consecutive dwords (2-way bank alias = free).
// Per iter: 1 ds_read_b64 + 1 ds_min amortized over 8 pixel-pairs.
// dx values are EXACT: gt coords are multiples of 2^-15 < 512, s+64k integers,
// so (s+64k)-gx fits in 24 bits of mantissa at 2^-15 granularity.
// Workspace poison contract (0xAA): g_cm uint-min identity (0xAAAAAAAA > any
// positive-float bits); sums poison -3.03e-13f absorbed by fp32 +=; cnt
// last-block check accepts POISON+511 (and 511 fallback).
__launch_bounds__(512, 4)
__global__ void chamfer_fused(const float* __restrict__ prob,
                              const float* __restrict__ gt,
                              float* __restrict__ out,
                              float* __restrict__ sums,        // [0]=sum p, [1]=sum p*d
                              unsigned int* __restrict__ cnt,
                              unsigned int* __restrict__ g_cm) // [16 slots][512]
{
    __shared__ float2 dg_s[1024];        // 8 chunks x 128 (mirrored) {dy^2, gx}
    __shared__ unsigned int cm_s[1024];  // mirrored column-min bits
    __shared__ unsigned int rm_s[512];   // per-pixel row-min d^2 bits
    __shared__ float p_s[512];
    __shared__ float red[16];
    __shared__ int last_s;

    const int t = threadIdx.x;
    const int row = blockIdx.x;
    const int g = t >> 6;
    const int s = t & 63;
    const float maxd = __builtin_sqrtf(524288.0f);   // sqrt(512^2+512^2)
    const float eod = EPSF / maxd;

    // ---- stage GT (chunk-mirrored: dg_s[c*128 + q] = GT[c*64 + (q&63)])
    {
        float2 gv = ((const float2*)gt)[t];          // (gy, gx); t is the GT idx
        float dy = (float)row - gv.x;
        float2 v = make_float2(dy * dy, gv.y);
        dg_s[(g << 7) + s]      = v;
        dg_s[(g << 7) + 64 + s] = v;
    }
    cm_s[t]       = INFB;
    cm_s[t + 512] = INFB;
    rm_s[t]       = INFB;
    p_s[t] = prob[(row << 9) + t];
    __syncthreads();

    // ---- per-pixel constants for the 8 owned pixels x = s + 64k
    float inv[8], ei[8], rm[8];
#pragma unroll
    for (int k = 0; k < 8; ++k) {
        float p = p_s[s + (k << 6)];
        float q = p * p;
        float iv = 1.0f / (q * q + eod);
        inv[k] = iv;
        ei[k] = EPSF * iv;
        rm[k] = 3e38f;
    }
    const float sf = (float)s;

    // ---- main loop: 64 GT points, 8 pixels each
    int j = (g << 7) + s;
#pragma unroll 4
    for (int i = 0; i < 64; ++i, ++j) {
        float2 gc = dg_s[j];                         // mirror: j+63 stays in chunk
        float dx0 = sf - gc.y;
        float vm;
#pragma unroll
        for (int k = 0; k < 8; ++k) {
            float dx = dx0 + (float)(k << 6);
            float d2 = fmaf(dx, dx, gc.x);
            rm[k] = fminf(rm[k], d2);
            float d = __builtin_amdgcn_sqrtf(d2);
            float vv = fmaf(d, inv[k], ei[k]);       // (d+eps)*inv = d*inv + eps*inv
            vm = k ? fminf(vm, vv) : vv;
        }
        atomicMin(&cm_s[j], __float_as_uint(vm));    // 64 consecutive dwords/wave
    }

    // ---- row-min merge across the 8 GT groups (positive floats: bit-ordered)
#pragma unroll
    for (int k = 0; k < 8; ++k)
        atomicMin(&rm_s[s + (k << 6)], __float_as_uint(rm[k]));
    __syncthreads();

    // ---- column merge (fold mirror halves), scatter into 16 global slots
    {
        unsigned int a = min(cm_s[(g << 7) + s], cm_s[(g << 7) + 64 + s]);
        atomicMin(&g_cm[((row & 15) << 9) + t], a);  // col index == t
    }

    // ---- term1 partials
    float dmin = __builtin_amdgcn_sqrtf(__uint_as_float(rm_s[t]));
    float pv = wave_sum(p_s[t] * dmin);
    float sp = wave_sum(p_s[t]);
    if ((t & 63) == 0) { red[t >> 6] = pv; red[8 + (t >> 6)] = sp; }
    __syncthreads();
    if (t == 0) {
        float a = 0.f, b = 0.f;
#pragma unroll
        for (int i = 0; i < 8; ++i) { a += red[i]; b += red[8 + i]; }
        atomicAdd(&sums[1], a);
        atomicAdd(&sums[0], b);
        __threadfence();
        unsigned int old = atomicAdd(cnt, 1u);
        last_s = (old == POISON + 511u) || (old == 511u);
    }
    __syncthreads();
    if (!last_s) return;

    // ---- last block finalizes
    __threadfence();
    unsigned int mv = __hip_atomic_load(&g_cm[t], __ATOMIC_RELAXED, __HIP_MEMORY_SCOPE_AGENT);
#pragma unroll
    for (int sl = 1; sl < 16; ++sl) {
        unsigned int u = __hip_atomic_load(&g_cm[(sl << 9) + t], __ATOMIC_RELAXED, __HIP_MEMORY_SCOPE_AGENT);
        mv = (u < mv) ? u : mv;
    }
    float v = fminf(fmaxf(__uint_as_float(mv), 0.0f), maxd);
    float s2 = wave_sum(v);
    if ((t & 63) == 0) red[t >> 6] = s2;
    __syncthreads();
    if (t == 0) {
        float tsum = 0.f;
#pragma unroll
        for (int i = 0; i < 8; ++i) tsum += red[i];
        float term2 = tsum * (1.0f / 512.0f);
        float sA = __hip_atomic_load(&sums[0], __ATOMIC_RELAXED, __HIP_MEMORY_SCOPE_AGENT);
        float sB = __hip_atomic_load(&sums[1], __ATOMIC_RELAXED, __HIP_MEMORY_SCOPE_AGENT);
        out[0] = sB / (sA + EPSF) + term2;
    }
}

extern "C" void kernel_launch(void* const* d_in, const int* in_sizes, int n_in,
                              void* d_out, int out_size, void* d_ws, size_t ws_size,
                              hipStream_t stream) {
    const float* prob = (const float*)d_in[0];   // [512*512]
    const float* gt   = (const float*)d_in[1];   // [512,2]
    // d_in[2] (all_img_locations) implicit from pixel index; unused.
    float* out = (float*)d_out;

    float* sums        = (float*)d_ws;                        // 8 B
    unsigned int* cnt  = (unsigned int*)((char*)d_ws + 8);    // 4 B
    unsigned int* g_cm = (unsigned int*)((char*)d_ws + 128);  // 16*512*4 = 32 KB

    chamfer_fused<<<512, 512, 0, stream>>>(prob, gt, out, sums, cnt, g_cm);
}